// Round 1
// baseline (612.062 us; speedup 1.0000x reference)
//
#include <hip/hip_runtime.h>

// CRF log-likelihood, round 8: single-wave scan, fully in-register state.
//
// Key identity (round-6/7-verified layouts): for mfma_f32_16x16x32_bf16,
// C/D row = 4*(lane>>4)+reg, col = lane&15; B-frag k = 32c + 16*(jj>>2)
// + 4*(lane>>4) + (jj&3), col = lane&15. Hence a wave holding ALL 8
// m-tiles (full 128-row state x 16 batches) feeds its own next-step B
// fragments from its own C registers: mt = 2c+(jj>>2), r = jj&3.
// => no LDS state round-trip, no __syncthreads, no inter-wave skew.
//
// crf_scan grid = 96 blocks x 256 thr:
//   blocks 0..15  : FORWARD scan (wave 0 only after the sort; waves 1-3
//                   help the bitonic sort then exit).
//   blocks 16..31 : BACKWARD scan, same structure.
//   blocks 32..95 : unary+binary scores (4 batches each), unchanged.
// Per scan wave: E matrix in 128 VGPRs (af[8][4] bf16x8), u-ring depth 4
// in 128 VGPRs (only vmem in the loop -> precise vmcnt), accs 32 VGPRs.
// Renorm: lag-1 ci = rcp(S0_prev), S0 broadcast via ds_bpermute (lane b).
// bwd inj folded to rv = cis*s + injf (cis/injf per-batch scalars).
// Captures -> LDS (lgkm only), copied to qcap/rcap after the loop.
// crf_comb: logZ = ln2*(log2(dot(qcap,rcap)) + Dq + Dr); out = score - logZ.

#define B_   256
#define LL   1024
#define TT   128
#define NBLK 16
#define L2E  1.4426950408889634f
#define LN2f 0.6931471805599453f

typedef __attribute__((ext_vector_type(8))) short bf16x8;
typedef __attribute__((ext_vector_type(4))) float f32x4;
union bfrw { unsigned w[4]; bf16x8 v; };

__device__ __forceinline__ unsigned bfround(float x) {   // RNE bf16 bits in [31:16]
    unsigned u = __float_as_uint(x);
    return u + 0x7fffu + ((u >> 16) & 1u);
}
__device__ __forceinline__ unsigned pack2(float lo, float hi) {  // [hi|lo] bf16 pair
#if __has_builtin(__builtin_amdgcn_cvt_pk_bf16_f32)
    auto p = __builtin_amdgcn_cvt_pk_bf16_f32(lo, hi);
    unsigned w; __builtin_memcpy(&w, &p, 4); return w;
#else
    return __builtin_amdgcn_perm(bfround(hi), bfround(lo), 0x07060302);
#endif
}

template<bool FWD, int PH>
__device__ __forceinline__ void phase1(int t, float& Dacc, float& sprev,
                                       float4 (&up)[4][8],
                                       const bf16x8 (&af)[8][4],
                                       bf16x8 (&bfr)[4],
                                       const float* pu,
                                       float* capl, float* dcap,
                                       int cb, int tfin, int q, int b)
{
    constexpr int SLOT = FWD ? ((1 + PH) & 3) : ((3 - PH) & 3);

    // ---- 32 MFMA: 8 m-tiles, chained over 4 k-blocks ----
    f32x4 acc[8];
    #pragma unroll
    for (int mt = 0; mt < 8; ++mt)
        acc[mt] = __builtin_amdgcn_mfma_f32_16x16x32_bf16(
            af[mt][0], bfr[0], (f32x4){0.f, 0.f, 0.f, 0.f}, 0, 0, 0);
    #pragma unroll
    for (int c = 1; c < 4; ++c) {
        #pragma unroll
        for (int mt = 0; mt < 8; ++mt)
            acc[mt] = __builtin_amdgcn_mfma_f32_16x16x32_bf16(
                af[mt][c], bfr[c], acc[mt], 0, 0, 0);
    }

    // u_t (fwd) / u_{t-1} (bwd) from ring; exp issues under MFMA latency
    float ex[8][4];
    #pragma unroll
    for (int mt = 0; mt < 8; ++mt) {
        float4 v = up[SLOT][mt];
        ex[mt][0] = __builtin_amdgcn_exp2f(v.x * L2E);
        ex[mt][1] = __builtin_amdgcn_exp2f(v.y * L2E);
        ex[mt][2] = __builtin_amdgcn_exp2f(v.z * L2E);
        ex[mt][3] = __builtin_amdgcn_exp2f(v.w * L2E);
    }
    {   // prefetch into the freed slot (consumed 4 steps later)
        int tp = FWD ? (t + 4) : (t - 5);
        tp = tp < 0 ? 0 : (tp > LL - 1 ? LL - 1 : tp);
        const float* pt = pu + (size_t)tp * TT;
        #pragma unroll
        for (int mt = 0; mt < 8; ++mt)
            up[SLOT][mt] = *(const float4*)(pt + mt * 16);
    }

    // lag-1 renorm scalars (per-batch, uniform over the lane's 32 values)
    float ci = __builtin_amdgcn_rcpf(sprev);
    float lg = __builtin_amdgcn_logf(sprev);          // v_log_f32 = log2
    bool inj = (!FWD) && (tfin == t - 1);
    float cis  = inj ? 0.f : ci;
    float injf = inj ? 1.f : 0.f;
    Dacc = inj ? 0.f : (Dacc + lg);

    float rv[8][4];
    #pragma unroll
    for (int mt = 0; mt < 8; ++mt) {
        #pragma unroll
        for (int r = 0; r < 4; ++r)
            rv[mt][r] = cis * acc[mt][r] + injf;      // inj folded into fma
    }

    if (!FWD) {
        bool cap = (cb == t - 1) && (cb != tfin);     // cap => !inj
        if (__any(cap)) {
            if (cap) {
                #pragma unroll
                for (int mt = 0; mt < 8; ++mt) {
                    float4 c4 = {rv[mt][0], rv[mt][1], rv[mt][2], rv[mt][3]};
                    *(float4*)(capl + b * TT + mt * 16 + q * 4) = c4;
                }
                if (q == 0) dcap[b] = Dacc;
            }
        }
    }

    float ov[8][4];
    #pragma unroll
    for (int mt = 0; mt < 8; ++mt) {
        #pragma unroll
        for (int r = 0; r < 4; ++r)
            ov[mt][r] = ex[mt][r] * rv[mt][r];
    }

    if (FWD) {
        bool cap = (cb == t);
        if (__any(cap)) {
            if (cap) {
                #pragma unroll
                for (int mt = 0; mt < 8; ++mt) {
                    float4 c4 = {ov[mt][0], ov[mt][1], ov[mt][2], ov[mt][3]};
                    *(float4*)(capl + b * TT + mt * 16 + q * 4) = c4;
                }
                if (q == 0) dcap[b] = Dacc;
            }
        }
    }

    // raw S0 broadcast for next step: j=0 lives in lane b (q=0), acc[0] elem 0
    {
        int s0i = __float_as_int(acc[0][0]);
        int sp  = __builtin_amdgcn_ds_bpermute(b << 2, s0i);
        sprev = __int_as_float(sp);
    }

    // next-step B fragments, fully in-register (identity above)
    #pragma unroll
    for (int c = 0; c < 4; ++c) {
        bfrw pk;
        pk.w[0] = pack2(ov[2*c][0],     ov[2*c][1]);
        pk.w[1] = pack2(ov[2*c][2],     ov[2*c][3]);
        pk.w[2] = pack2(ov[2*c+1][0],   ov[2*c+1][1]);
        pk.w[3] = pack2(ov[2*c+1][2],   ov[2*c+1][3]);
        bfr[c] = pk.v;
    }
}

__launch_bounds__(256, 1)
__global__ void crf_scan(const float* __restrict__ inputs,
                         const int*   __restrict__ tags,
                         const int*   __restrict__ slens,
                         const float* __restrict__ trans,
                         float* __restrict__ qcap, float* __restrict__ rcap,
                         float* __restrict__ dqv,  float* __restrict__ drv,
                         int* __restrict__ perm, float* __restrict__ scorebuf)
{
    __shared__ __align__(16) float capl[16 * TT];   // per-block capture buffer
    __shared__ float dcap[16];
    __shared__ float sb[2 * 16];                    // score-path partials
    __shared__ int keys[B_];

    const int tid = threadIdx.x;

    // ---------------- score blocks (32..95): 4 batches each ----------------
    if (blockIdx.x >= 2 * NBLK) {
        const int sbid = blockIdx.x - 2 * NBLK;     // 0..63
        const int lane = tid & 63, wid = tid >> 6;
        #pragma unroll 1
        for (int bi = 0; bi < 4; ++bi) {
            const int b = sbid * 4 + bi;
            const int slen = slens[b];
            const float* inb  = inputs + (size_t)b * LL * TT;
            const int*   tagb = tags + b * LL;
            float sc = 0.f;
            for (int t = tid; t < slen; t += 256) {
                int tg = tagb[t];
                float v = inb[(size_t)t * TT + tg];
                if (t >= 1) v += trans[tagb[t - 1] * TT + tg];
                sc += v;
            }
            #pragma unroll
            for (int off = 32; off > 0; off >>= 1) sc += __shfl_xor(sc, off, 64);
            if (lane == 0) sb[wid] = sc;
            __syncthreads();
            if (tid == 0) scorebuf[b] = sb[0] + sb[1] + sb[2] + sb[3];
            __syncthreads();
        }
        return;
    }

    // ---------------- scan blocks (0..31) ----------------
    // deterministic bitonic sort of (slen, batch) keys — all 256 threads
    keys[tid] = slens[tid] * 256 + tid;
    __syncthreads();
    for (int k = 2; k <= B_; k <<= 1) {
        for (int s = k >> 1; s > 0; s >>= 1) {
            int ixj = tid ^ s;
            if (ixj > tid) {
                int a = keys[tid], b2 = keys[ixj];
                bool asc = ((tid & k) == 0);
                if ((a > b2) == asc) { keys[tid] = b2; keys[ixj] = a; }
            }
            __syncthreads();
        }
    }

    const bool isf = (blockIdx.x < NBLK);
    const int g    = isf ? blockIdx.x : blockIdx.x - NBLK;
    if (isf && tid < 16) perm[g * 16 + tid] = keys[g * 16 + tid] & 255;

    if (tid >= 64) return;            // waves 1..3 done; wave 0 scans alone

    const int q = tid >> 4;           // quad 0..3
    const int b = tid & 15;           // batch slot 0..15

    const int key = keys[g * 16 + b];
    const int ob  = key & 255;
    const int sl  = key >> 8;
    int tfin = sl - 1; if (tfin < 1) tfin = 1;

    int tmax = tfin;
    #pragma unroll
    for (int o = 1; o < 16; o <<= 1) {
        int c2 = __shfl_xor(tmax, o, 16); tmax = c2 > tmax ? c2 : tmax;
    }
    tmax = __builtin_amdgcn_readfirstlane(tmax);

    const int C  = (tmax + 4) >> 1;             // balanced cut (>=2)
    const int cb = tfin < C ? tfin : C;

    int cmax = cb, cmin = cb;
    #pragma unroll
    for (int o = 1; o < 16; o <<= 1) {
        int a = __shfl_xor(cmax, o, 16); cmax = a > cmax ? a : cmax;
        int b2 = __shfl_xor(cmin, o, 16); cmin = b2 < cmin ? b2 : cmin;
    }
    cmax = __builtin_amdgcn_readfirstlane(cmax);
    cmin = __builtin_amdgcn_readfirstlane(cmin);

    // full E matrix in registers: j = 16*mt + b (A-row = lane&15),
    // k = 32c + 16*(jj>>2) + 4*q + (jj&3) (round-6-verified layout)
    bf16x8 af[8][4];
    #pragma unroll
    for (int mt = 0; mt < 8; ++mt) {
        const int j = 16 * mt + b;
        #pragma unroll
        for (int c = 0; c < 4; ++c) {
            #pragma unroll
            for (int jj = 0; jj < 8; ++jj) {
                int k = 32 * c + 16 * (jj >> 2) + 4 * q + (jj & 3);
                int idx = isf ? (k * TT + j) : (j * TT + k);
                float ev = __builtin_amdgcn_exp2f(trans[idx] * L2E);
                af[mt][c][jj] = (short)(bfround(ev) >> 16);
            }
        }
    }

    const float* pu = inputs + (size_t)ob * LL * TT + q * 4;
    float Dacc = 0.f, sprev = 1.0f;
    float4 up[4][8];
    bf16x8 bfr[4];

    if (isf) {
        // init q0 = exp(in[0][j]) packed to B-frags (cb >= 1: no init capture)
        float q0[8][4];
        #pragma unroll
        for (int mt = 0; mt < 8; ++mt) {
            float4 v = *(const float4*)(pu + mt * 16);
            q0[mt][0] = __builtin_amdgcn_exp2f(v.x * L2E);
            q0[mt][1] = __builtin_amdgcn_exp2f(v.y * L2E);
            q0[mt][2] = __builtin_amdgcn_exp2f(v.z * L2E);
            q0[mt][3] = __builtin_amdgcn_exp2f(v.w * L2E);
        }
        #pragma unroll
        for (int c = 0; c < 4; ++c) {
            bfrw pk;
            pk.w[0] = pack2(q0[2*c][0],   q0[2*c][1]);
            pk.w[1] = pack2(q0[2*c][2],   q0[2*c][3]);
            pk.w[2] = pack2(q0[2*c+1][0], q0[2*c+1][1]);
            pk.w[3] = pack2(q0[2*c+1][2], q0[2*c+1][3]);
            bfr[c] = pk.v;
        }
        #pragma unroll
        for (int s = 1; s <= 4; ++s) {
            int tp = s > LL - 1 ? LL - 1 : s;
            #pragma unroll
            for (int mt = 0; mt < 8; ++mt)
                up[s & 3][mt] = *(const float4*)(pu + (size_t)tp * TT + mt * 16);
        }

        for (int tb = 1; tb <= cmax; tb += 4) {
            phase1<true,0>(tb+0, Dacc, sprev, up, af, bfr, pu, capl, dcap, cb, tfin, q, b);
            phase1<true,1>(tb+1, Dacc, sprev, up, af, bfr, pu, capl, dcap, cb, tfin, q, b);
            phase1<true,2>(tb+2, Dacc, sprev, up, af, bfr, pu, capl, dcap, cb, tfin, q, b);
            phase1<true,3>(tb+3, Dacc, sprev, up, af, bfr, pu, capl, dcap, cb, tfin, q, b);
        }
    } else {
        // init w = 1.0; batches with cb == tfin capture ones / Dr = 0 here
        {
            bfrw pk;
            pk.w[0] = pk.w[1] = pk.w[2] = pk.w[3] = 0x3F803F80u;
            #pragma unroll
            for (int c = 0; c < 4; ++c) bfr[c] = pk.v;
        }
        if (cb == tfin) {
            float4 one4 = {1.f, 1.f, 1.f, 1.f};
            #pragma unroll
            for (int mt = 0; mt < 8; ++mt)
                *(float4*)(capl + b * TT + mt * 16 + q * 4) = one4;
            if (q == 0) dcap[b] = 0.f;
        }

        const int tb0 = (tmax + 4) & ~3;   // >= tmax+1, == 0 mod 4
        #pragma unroll
        for (int ph = 0; ph < 4; ++ph) {
            int ui = tb0 - 1 - ph;
            ui = ui > LL - 1 ? LL - 1 : (ui < 0 ? 0 : ui);
            #pragma unroll
            for (int mt = 0; mt < 8; ++mt)
                up[(3 - ph) & 3][mt] = *(const float4*)(pu + (size_t)ui * TT + mt * 16);
        }

        for (int tb = tb0; tb > cmin; tb -= 4) {
            phase1<false,0>(tb-0, Dacc, sprev, up, af, bfr, pu, capl, dcap, cb, tfin, q, b);
            phase1<false,1>(tb-1, Dacc, sprev, up, af, bfr, pu, capl, dcap, cb, tfin, q, b);
            phase1<false,2>(tb-2, Dacc, sprev, up, af, bfr, pu, capl, dcap, cb, tfin, q, b);
            phase1<false,3>(tb-3, Dacc, sprev, up, af, bfr, pu, capl, dcap, cb, tfin, q, b);
        }
    }

    // copy captures out (single wave: only need own LDS writes drained)
    asm volatile("s_waitcnt lgkmcnt(0)" ::: "memory");
    float* gout = isf ? qcap : rcap;
    #pragma unroll
    for (int i = 0; i < 8; ++i) {
        float4 v = *(const float4*)(capl + i * 256 + tid * 4);
        *(float4*)(gout + (size_t)g * 16 * TT + i * 256 + tid * 4) = v;
    }
    if (tid < 16) (isf ? dqv : drv)[g * 16 + tid] = dcap[tid];
}

__global__ void crf_comb(const float* __restrict__ qcap, const float* __restrict__ rcap,
                         const float* __restrict__ dqv, const float* __restrict__ drv,
                         const int* __restrict__ perm, const float* __restrict__ scorebuf,
                         float* __restrict__ out) {
    const int tid = threadIdx.x;
    const int r16 = tid >> 4, part = tid & 15;
    const int rank = blockIdx.x * 16 + r16;
    const float* qc = qcap + rank * TT + part * 8;
    const float* rc = rcap + rank * TT + part * 8;
    float4 a0 = *(const float4*)(qc);
    float4 a1 = *(const float4*)(qc + 4);
    float4 b0 = *(const float4*)(rc);
    float4 b1 = *(const float4*)(rc + 4);
    float s = a0.x*b0.x + a0.y*b0.y + a0.z*b0.z + a0.w*b0.w
            + a1.x*b1.x + a1.y*b1.y + a1.z*b1.z + a1.w*b1.w;
    #pragma unroll
    for (int o = 1; o < 16; o <<= 1) s += __shfl_xor(s, o, 16);
    if (part == 0) {
        int ob = perm[rank];
        float logZ = LN2f * (__builtin_amdgcn_logf(s) + dqv[rank] + drv[rank]);
        out[ob] = scorebuf[ob] - logZ;
    }
}

extern "C" void kernel_launch(void* const* d_in, const int* in_sizes, int n_in,
                              void* d_out, int out_size, void* d_ws, size_t ws_size,
                              hipStream_t stream) {
    const float* inputs = (const float*)d_in[0];
    const int*   tags   = (const int*)d_in[1];
    const int*   slens  = (const int*)d_in[2];
    const float* trans  = (const float*)d_in[3];
    float* out = (float*)d_out;

    float* qcap = (float*)d_ws;            // 256*128 f32
    float* rcap = qcap + 32768;            // 256*128 f32
    float* dqv  = rcap + 32768;            // 256
    float* drv  = dqv + 256;               // 256
    int*   perm = (int*)(drv + 256);       // 256
    float* scorebuf = (float*)(perm + 256);// 256

    crf_scan<<<2 * NBLK + 64, 256, 0, stream>>>(inputs, tags, slens, trans,
                                                qcap, rcap, dqv, drv, perm, scorebuf);
    crf_comb<<<NBLK, 256, 0, stream>>>(qcap, rcap, dqv, drv, perm, scorebuf, out);
}

// Round 2
// 485.496 us; speedup vs baseline: 1.2607x; 1.2607x over previous
//
#include <hip/hip_runtime.h>

// CRF log-likelihood, round 9: 2-wave scan — half state in-register via the
// C/D->B identity, half exchanged per step through LDS.
//
// Identity (round-6/8-verified): mfma_f32_16x16x32_bf16 C/D row =
// 4*(lane>>4)+reg, col = lane&15; B-frag k = 32c + 16*(jj>>2) + 4*(lane>>4)
// + (jj&3), col = lane&15. A wave owning m-tiles {4W..4W+3} (rows 64W..64W+63)
// self-supplies B k-blocks c = {2W, 2W+1} from its own C registers and reads
// the other two (partner's) from LDS: 2 ds_write_b128 + 2 ds_read_b128 +
// 1 barrier per step (vs r7: 4 waves x (4 reads + 1 write); vs r8: 1 wave
// doing 4x the issue work serially).
//
// crf_scan grid = 96 blocks x 256 thr:
//   blocks 0..15  : FORWARD scan on waves 0-1; waves 2-3 run a matched
//                   dummy-barrier loop (barrier counts must agree).
//   blocks 16..31 : BACKWARD scan, same structure.
//   blocks 32..95 : unary+binary scores (4 batches each), concurrent.
// Per scan wave/step: 16 MFMA (8 depth-2 chains + f32x4 merge, self k-blocks
// first so partner ds_read latency hides), 16 exp2 under MFMA shadow, 4-deep
// u prefetch ring (4 global_load_dwordx4, only vmem in loop), lag-1 renorm
// via LDS scalar sbuf (raw S0 from row 0, wave 0), bwd inj folded into fma.
// Captures -> LDS capl, copied out once. crf_comb unchanged.

#define B_   256
#define LL   1024
#define TT   128
#define NBLK 16
#define L2E  1.4426950408889634f
#define LN2f 0.6931471805599453f

typedef __attribute__((ext_vector_type(8))) short bf16x8;
typedef __attribute__((ext_vector_type(4))) float f32x4;
union bfrw { unsigned w[4]; bf16x8 v; };

__device__ __forceinline__ unsigned bfround(float x) {   // RNE bf16 bits in [31:16]
    unsigned u = __float_as_uint(x);
    return u + 0x7fffu + ((u >> 16) & 1u);
}
__device__ __forceinline__ unsigned pack2(float lo, float hi) {  // [hi|lo] bf16 pair
#if __has_builtin(__builtin_amdgcn_cvt_pk_bf16_f32)
    auto p = __builtin_amdgcn_cvt_pk_bf16_f32(lo, hi);
    unsigned w; __builtin_memcpy(&w, &p, 4); return w;
#else
    return __builtin_amdgcn_perm(bfround(hi), bfround(lo), 0x07060302);
#endif
}
__device__ __forceinline__ void lds_barrier() {
    asm volatile("s_waitcnt lgkmcnt(0)\n\ts_barrier" ::: "memory");
}

// fragls layout: [buf 0/1][cg 0..3][lane 0..63] x 16B. Wave W writes cg =
// {2W, 2W+1} (its packed next-state frags), reads cg = {2-2W, 3-2W}.
// af[m][i]: chain slot i -> global k-block c = (i<2) ? 2W+i : 2(1-W)+(i-2),
// so slots 0,1 are always the in-register self frags bs[0], bs[1].

template<bool FWD, int PH>
__device__ __forceinline__ void phase2(int t, float& Dacc,
                                       float4 (&up)[4][4],
                                       const bf16x8 (&af)[4][4],
                                       bf16x8 (&bs)[2],
                                       short* fragls, float* sbuf,
                                       const float* pu,
                                       float* capl, float* dcap,
                                       int cb, int tfin,
                                       int W, int q, int b, int lane)
{
    constexpr int CUR  = PH & 1;
    constexpr int NXT  = CUR ^ 1;
    constexpr int SLOT = FWD ? ((1 + PH) & 3) : ((3 - PH) & 3);

    // partner frags (chain slots 2,3) + lag-1 scale, from LDS buf CUR
    const int po = (1 - W) * 2;
    bf16x8 bo0 = *(const bf16x8*)(fragls + (CUR * 4 + po) * 512 + lane * 8);
    bf16x8 bo1 = *(const bf16x8*)(fragls + (CUR * 4 + po + 1) * 512 + lane * 8);
    float sprev = sbuf[CUR * 16 + b];

    // ---- 16 MFMA: 8 independent depth-2 chains; self slots issue first so
    // the bo0/bo1 ds_read latency hides under them ----
    f32x4 ae[4], ao[4];
    #pragma unroll
    for (int m = 0; m < 4; ++m)
        ae[m] = __builtin_amdgcn_mfma_f32_16x16x32_bf16(af[m][0], bs[0],
                (f32x4){0.f, 0.f, 0.f, 0.f}, 0, 0, 0);
    #pragma unroll
    for (int m = 0; m < 4; ++m)
        ao[m] = __builtin_amdgcn_mfma_f32_16x16x32_bf16(af[m][1], bs[1],
                (f32x4){0.f, 0.f, 0.f, 0.f}, 0, 0, 0);
    #pragma unroll
    for (int m = 0; m < 4; ++m)
        ae[m] = __builtin_amdgcn_mfma_f32_16x16x32_bf16(af[m][2], bo0, ae[m], 0, 0, 0);
    #pragma unroll
    for (int m = 0; m < 4; ++m)
        ao[m] = __builtin_amdgcn_mfma_f32_16x16x32_bf16(af[m][3], bo1, ao[m], 0, 0, 0);

    // u from ring; exp2 issues under MFMA latency (trans pipe)
    float ex[4][4];
    #pragma unroll
    for (int m = 0; m < 4; ++m) {
        float4 v = up[SLOT][m];
        ex[m][0] = __builtin_amdgcn_exp2f(v.x * L2E);
        ex[m][1] = __builtin_amdgcn_exp2f(v.y * L2E);
        ex[m][2] = __builtin_amdgcn_exp2f(v.z * L2E);
        ex[m][3] = __builtin_amdgcn_exp2f(v.w * L2E);
    }
    {   // prefetch into the freed slot (consumed 4 steps later)
        int tp = FWD ? (t + 4) : (t - 5);
        tp = tp < 0 ? 0 : (tp > LL - 1 ? LL - 1 : tp);
        const float* pt = pu + (size_t)tp * TT;
        #pragma unroll
        for (int m = 0; m < 4; ++m)
            up[SLOT][m] = *(const float4*)(pt + m * 16);
    }

    // lag-1 renorm scalars (uniform per batch column b)
    float ci = __builtin_amdgcn_rcpf(sprev);
    float lg = __builtin_amdgcn_logf(sprev);          // v_log_f32 = log2
    bool inj = (!FWD) && (tfin == t - 1);
    float cis  = inj ? 0.f : ci;
    float injf = inj ? 1.f : 0.f;
    Dacc = inj ? 0.f : (Dacc + lg);

    f32x4 acc[4];
    #pragma unroll
    for (int m = 0; m < 4; ++m) acc[m] = ae[m] + ao[m];

    float rv[4][4];
    #pragma unroll
    for (int m = 0; m < 4; ++m) {
        #pragma unroll
        for (int r = 0; r < 4; ++r)
            rv[m][r] = cis * acc[m][r] + injf;        // inj folded into fma
    }

    if (!FWD) {
        bool cap = (cb == t - 1) && (cb != tfin);     // cap => !inj
        if (__any(cap)) {
            if (cap) {
                #pragma unroll
                for (int m = 0; m < 4; ++m) {
                    float4 c4 = {rv[m][0], rv[m][1], rv[m][2], rv[m][3]};
                    *(float4*)(capl + b * TT + 64 * W + m * 16 + q * 4) = c4;
                }
                if (W == 0 && q == 0) dcap[b] = Dacc;
            }
        }
    }

    float ov[4][4];
    #pragma unroll
    for (int m = 0; m < 4; ++m) {
        #pragma unroll
        for (int r = 0; r < 4; ++r)
            ov[m][r] = ex[m][r] * rv[m][r];
    }

    if (FWD) {
        bool cap = (cb == t);
        if (__any(cap)) {
            if (cap) {
                #pragma unroll
                for (int m = 0; m < 4; ++m) {
                    float4 c4 = {ov[m][0], ov[m][1], ov[m][2], ov[m][3]};
                    *(float4*)(capl + b * TT + 64 * W + m * 16 + q * 4) = c4;
                }
                if (W == 0 && q == 0) dcap[b] = Dacc;
            }
        }
    }

    // raw S0 for next step's renorm: global row 0 = wave 0, m=0, q=0, reg 0
    if (W == 0 && q == 0) sbuf[NXT * 16 + b] = acc[0][0];

    // pack self next-state frags (identity: frag f <- m-tiles {2f, 2f+1})
    bfrw p0, p1;
    p0.w[0] = pack2(ov[0][0], ov[0][1]);
    p0.w[1] = pack2(ov[0][2], ov[0][3]);
    p0.w[2] = pack2(ov[1][0], ov[1][1]);
    p0.w[3] = pack2(ov[1][2], ov[1][3]);
    p1.w[0] = pack2(ov[2][0], ov[2][1]);
    p1.w[1] = pack2(ov[2][2], ov[2][3]);
    p1.w[2] = pack2(ov[3][0], ov[3][1]);
    p1.w[3] = pack2(ov[3][2], ov[3][3]);
    bs[0] = p0.v;
    bs[1] = p1.v;
    const int so = W * 2;
    *(bf16x8*)(fragls + (NXT * 4 + so) * 512 + lane * 8)     = p0.v;
    *(bf16x8*)(fragls + (NXT * 4 + so + 1) * 512 + lane * 8) = p1.v;

    lds_barrier();
}

__launch_bounds__(256, 1)
__global__ void crf_scan(const float* __restrict__ inputs,
                         const int*   __restrict__ tags,
                         const int*   __restrict__ slens,
                         const float* __restrict__ trans,
                         float* __restrict__ qcap, float* __restrict__ rcap,
                         float* __restrict__ dqv,  float* __restrict__ drv,
                         int* __restrict__ perm, float* __restrict__ scorebuf)
{
    __shared__ __align__(16) short fragls[2 * 4 * 512];   // 8 KB exchange
    __shared__ __align__(16) float capl[16 * TT];         // 8 KB captures
    __shared__ float dcap[16];
    __shared__ float sbuf[2 * 16];
    __shared__ float ssb[4];
    __shared__ int keys[B_];

    const int tid = threadIdx.x;

    // ---------------- score blocks (32..95): 4 batches each ----------------
    if (blockIdx.x >= 2 * NBLK) {
        const int sbid = blockIdx.x - 2 * NBLK;     // 0..63
        const int lane = tid & 63, w = tid >> 6;
        #pragma unroll 1
        for (int bi = 0; bi < 4; ++bi) {
            const int b = sbid * 4 + bi;
            const int slen = slens[b];
            const float* inb  = inputs + (size_t)b * LL * TT;
            const int*   tagb = tags + b * LL;
            float sc = 0.f;
            for (int t = tid; t < slen; t += 256) {
                int tg = tagb[t];
                float v = inb[(size_t)t * TT + tg];
                if (t >= 1) v += trans[tagb[t - 1] * TT + tg];
                sc += v;
            }
            #pragma unroll
            for (int off = 32; off > 0; off >>= 1) sc += __shfl_xor(sc, off, 64);
            if (lane == 0) ssb[w] = sc;
            __syncthreads();
            if (tid == 0) scorebuf[b] = ssb[0] + ssb[1] + ssb[2] + ssb[3];
            __syncthreads();
        }
        return;
    }

    // ---------------- scan blocks (0..31) ----------------
    // deterministic bitonic sort of (slen, batch) keys — all 256 threads
    keys[tid] = slens[tid] * 256 + tid;
    __syncthreads();
    for (int k = 2; k <= B_; k <<= 1) {
        for (int s = k >> 1; s > 0; s >>= 1) {
            int ixj = tid ^ s;
            if (ixj > tid) {
                int a = keys[tid], b2 = keys[ixj];
                bool asc = ((tid & k) == 0);
                if ((a > b2) == asc) { keys[tid] = b2; keys[ixj] = a; }
            }
            __syncthreads();
        }
    }

    const bool isf = (blockIdx.x < NBLK);
    const int g    = isf ? blockIdx.x : blockIdx.x - NBLK;
    if (isf && tid < 16) perm[g * 16 + tid] = keys[g * 16 + tid] & 255;

    const int lane = tid & 63;
    const int wid  = __builtin_amdgcn_readfirstlane(tid >> 6);
    const int q    = lane >> 4;
    const int b    = lane & 15;

    const int key = keys[g * 16 + b];
    const int ob  = key & 255;
    const int sl  = key >> 8;
    int tfin = sl - 1; if (tfin < 1) tfin = 1;

    int tmax = tfin;
    #pragma unroll
    for (int o = 1; o < 16; o <<= 1) {
        int c2 = __shfl_xor(tmax, o, 16); tmax = c2 > tmax ? c2 : tmax;
    }
    tmax = __builtin_amdgcn_readfirstlane(tmax);

    const int C  = (tmax + 4) >> 1;             // balanced cut (>=2)
    const int cb = tfin < C ? tfin : C;

    int cmax = cb, cmin = cb;
    #pragma unroll
    for (int o = 1; o < 16; o <<= 1) {
        int a = __shfl_xor(cmax, o, 16); cmax = a > cmax ? a : cmax;
        int b2 = __shfl_xor(cmin, o, 16); cmin = b2 < cmin ? b2 : cmin;
    }
    cmax = __builtin_amdgcn_readfirstlane(cmax);
    cmin = __builtin_amdgcn_readfirstlane(cmin);

    const int tb0 = (tmax + 4) & ~3;            // bwd start, == 0 mod 4
    const int ni  = isf ? (((cmax - 1) >> 2) + 1) : ((tb0 - cmin + 3) >> 2);

    if (wid >= 2) {                             // matched-barrier idle waves
        __syncthreads();
        for (int i = 0; i < ni * 4; ++i) lds_barrier();
        return;
    }

    const int W = wid;                          // 0 or 1: rows 64W..64W+63

    // E fragments: af[m][i], chain slot i -> global k-block
    // c = (i<2) ? 2W+i : 2(1-W)+(i-2); j = 64W + 16m + b (A-row = lane&15);
    // k = 32c + 16*(jj>>2) + 4q + (jj&3) (round-6-verified layout)
    bf16x8 af[4][4];
    #pragma unroll
    for (int m = 0; m < 4; ++m) {
        const int j = 64 * W + 16 * m + b;
        #pragma unroll
        for (int i = 0; i < 4; ++i) {
            const int c = (i < 2) ? (2 * W + i) : (2 * (1 - W) + (i - 2));
            #pragma unroll
            for (int jj = 0; jj < 8; ++jj) {
                int k = 32 * c + 16 * (jj >> 2) + 4 * q + (jj & 3);
                int idx = isf ? (k * TT + j) : (j * TT + k);
                float ev = __builtin_amdgcn_exp2f(trans[idx] * L2E);
                af[m][i][jj] = (short)(bfround(ev) >> 16);
            }
        }
    }

    const float* pu = inputs + (size_t)ob * LL * TT + 64 * W + q * 4;
    float Dacc = 0.f;
    float4 up[4][4];
    bf16x8 bs[2];
    const int so = W * 2;

    if (tid < 16) sbuf[tid] = 1.0f;             // initial scale (buf 0)

    if (isf) {
        // init q0 = exp(in[0][j]) -> self frags + LDS buf0 copies
        float q0[4][4];
        #pragma unroll
        for (int m = 0; m < 4; ++m) {
            float4 v = *(const float4*)(pu + m * 16);
            q0[m][0] = __builtin_amdgcn_exp2f(v.x * L2E);
            q0[m][1] = __builtin_amdgcn_exp2f(v.y * L2E);
            q0[m][2] = __builtin_amdgcn_exp2f(v.z * L2E);
            q0[m][3] = __builtin_amdgcn_exp2f(v.w * L2E);
        }
        bfrw p0, p1;
        p0.w[0] = pack2(q0[0][0], q0[0][1]);
        p0.w[1] = pack2(q0[0][2], q0[0][3]);
        p0.w[2] = pack2(q0[1][0], q0[1][1]);
        p0.w[3] = pack2(q0[1][2], q0[1][3]);
        p1.w[0] = pack2(q0[2][0], q0[2][1]);
        p1.w[1] = pack2(q0[2][2], q0[2][3]);
        p1.w[2] = pack2(q0[3][0], q0[3][1]);
        p1.w[3] = pack2(q0[3][2], q0[3][3]);
        bs[0] = p0.v; bs[1] = p1.v;
        *(bf16x8*)(fragls + (so) * 512 + lane * 8)     = p0.v;
        *(bf16x8*)(fragls + (so + 1) * 512 + lane * 8) = p1.v;

        #pragma unroll
        for (int s = 1; s <= 4; ++s) {
            #pragma unroll
            for (int m = 0; m < 4; ++m)
                up[s & 3][m] = *(const float4*)(pu + (size_t)s * TT + m * 16);
        }
        __syncthreads();

        for (int tb = 1; tb <= cmax; tb += 4) {
            phase2<true,0>(tb+0, Dacc, up, af, bs, fragls, sbuf, pu, capl, dcap, cb, tfin, W, q, b, lane);
            phase2<true,1>(tb+1, Dacc, up, af, bs, fragls, sbuf, pu, capl, dcap, cb, tfin, W, q, b, lane);
            phase2<true,2>(tb+2, Dacc, up, af, bs, fragls, sbuf, pu, capl, dcap, cb, tfin, W, q, b, lane);
            phase2<true,3>(tb+3, Dacc, up, af, bs, fragls, sbuf, pu, capl, dcap, cb, tfin, W, q, b, lane);
        }
    } else {
        // init w = 1.0; batches with cb == tfin capture ones / Dr = 0 here
        {
            bfrw pk;
            pk.w[0] = pk.w[1] = pk.w[2] = pk.w[3] = 0x3F803F80u;
            bs[0] = pk.v; bs[1] = pk.v;
            *(bf16x8*)(fragls + (so) * 512 + lane * 8)     = pk.v;
            *(bf16x8*)(fragls + (so + 1) * 512 + lane * 8) = pk.v;
        }
        if (cb == tfin) {
            float4 one4 = {1.f, 1.f, 1.f, 1.f};
            #pragma unroll
            for (int m = 0; m < 4; ++m)
                *(float4*)(capl + b * TT + 64 * W + m * 16 + q * 4) = one4;
            if (W == 0 && q == 0) dcap[b] = 0.f;
        }

        #pragma unroll
        for (int ph = 0; ph < 4; ++ph) {
            int ui = tb0 - 1 - ph;
            ui = ui > LL - 1 ? LL - 1 : (ui < 0 ? 0 : ui);
            #pragma unroll
            for (int m = 0; m < 4; ++m)
                up[(3 - ph) & 3][m] = *(const float4*)(pu + (size_t)ui * TT + m * 16);
        }
        __syncthreads();

        for (int tb = tb0; tb > cmin; tb -= 4) {
            phase2<false,0>(tb-0, Dacc, up, af, bs, fragls, sbuf, pu, capl, dcap, cb, tfin, W, q, b, lane);
            phase2<false,1>(tb-1, Dacc, up, af, bs, fragls, sbuf, pu, capl, dcap, cb, tfin, W, q, b, lane);
            phase2<false,2>(tb-2, Dacc, up, af, bs, fragls, sbuf, pu, capl, dcap, cb, tfin, W, q, b, lane);
            phase2<false,3>(tb-3, Dacc, up, af, bs, fragls, sbuf, pu, capl, dcap, cb, tfin, W, q, b, lane);
        }
    }

    // copy captures out (waves 0-1 = 128 threads; last lds_barrier synced us)
    float* gout = isf ? qcap : rcap;
    #pragma unroll
    for (int i = 0; i < 4; ++i) {
        float4 v = *(const float4*)(capl + i * 512 + tid * 4);
        *(float4*)(gout + (size_t)g * 16 * TT + i * 512 + tid * 4) = v;
    }
    if (tid < 16) (isf ? dqv : drv)[g * 16 + tid] = dcap[tid];
}

__global__ void crf_comb(const float* __restrict__ qcap, const float* __restrict__ rcap,
                         const float* __restrict__ dqv, const float* __restrict__ drv,
                         const int* __restrict__ perm, const float* __restrict__ scorebuf,
                         float* __restrict__ out) {
    const int tid = threadIdx.x;
    const int r16 = tid >> 4, part = tid & 15;
    const int rank = blockIdx.x * 16 + r16;
    const float* qc = qcap + rank * TT + part * 8;
    const float* rc = rcap + rank * TT + part * 8;
    float4 a0 = *(const float4*)(qc);
    float4 a1 = *(const float4*)(qc + 4);
    float4 b0 = *(const float4*)(rc);
    float4 b1 = *(const float4*)(rc + 4);
    float s = a0.x*b0.x + a0.y*b0.y + a0.z*b0.z + a0.w*b0.w
            + a1.x*b1.x + a1.y*b1.y + a1.z*b1.z + a1.w*b1.w;
    #pragma unroll
    for (int o = 1; o < 16; o <<= 1) s += __shfl_xor(s, o, 16);
    if (part == 0) {
        int ob = perm[rank];
        float logZ = LN2f * (__builtin_amdgcn_logf(s) + dqv[rank] + drv[rank]);
        out[ob] = scorebuf[ob] - logZ;
    }
}

extern "C" void kernel_launch(void* const* d_in, const int* in_sizes, int n_in,
                              void* d_out, int out_size, void* d_ws, size_t ws_size,
                              hipStream_t stream) {
    const float* inputs = (const float*)d_in[0];
    const int*   tags   = (const int*)d_in[1];
    const int*   slens  = (const int*)d_in[2];
    const float* trans  = (const float*)d_in[3];
    float* out = (float*)d_out;

    float* qcap = (float*)d_ws;            // 256*128 f32
    float* rcap = qcap + 32768;            // 256*128 f32
    float* dqv  = rcap + 32768;            // 256
    float* drv  = dqv + 256;               // 256
    int*   perm = (int*)(drv + 256);       // 256
    float* scorebuf = (float*)(perm + 256);// 256

    crf_scan<<<2 * NBLK + 64, 256, 0, stream>>>(inputs, tags, slens, trans,
                                                qcap, rcap, dqv, drv, perm, scorebuf);
    crf_comb<<<NBLK, 256, 0, stream>>>(qcap, rcap, dqv, drv, perm, scorebuf, out);
}

// Round 3
// 465.942 us; speedup vs baseline: 1.3136x; 1.0420x over previous
//
#include <hip/hip_runtime.h>

// CRF log-likelihood, round 10: fwd+bwd scans co-scheduled in ONE 512-thread
// block (2 waves/SIMD) so the two independent scans' stalls interleave.
//
// r7(4w)/r9(2w)/r8(1w) fit step = per-wave-work*2.2 + fixed: at 1 wave/SIMD
// every MFMA/LDS/trans stall is bare on the critical path. Fix: waves 0-3 =
// FORWARD scan of group g, waves 4-7 = BACKWARD scan of group g (independent,
// equal length by the balanced cut C). Shared per-step s_barrier; both sets
// run NS = max(ni_f, ni_b) iterations (overrun harmless: u clamps, captures
// and inj fire exactly once).
//
// Per wave: owns 2 m-tiles (32 rows = exactly one k-frag cg=W4). Self-
// supplies frag W4 from its own C registers (C/D->B identity, round-6/8-
// verified), reads the other 3 (ds_read_b128 x3), writes its frag (x1).
// 8 MFMA (2 m-tiles x depth-2x2 chains + merge), 8 exp2 under MFMA shadow,
// 4-deep u prefetch ring (2 global_load_dwordx4/step), lag-1 renorm via
// per-set sbuf, bwd inj folded into fma. Captures -> per-set LDS capl,
// copied out once.
//
// Grid = 80 blocks x 512: blocks 0..15 merged scans, 16..79 scores (4 ea).

#define B_   256
#define LL   1024
#define TT   128
#define NBLK 16
#define L2E  1.4426950408889634f
#define LN2f 0.6931471805599453f

typedef __attribute__((ext_vector_type(8))) short bf16x8;
typedef __attribute__((ext_vector_type(4))) float f32x4;
union bfrw { unsigned w[4]; bf16x8 v; };

__device__ __forceinline__ unsigned bfround(float x) {   // RNE bf16 bits in [31:16]
    unsigned u = __float_as_uint(x);
    return u + 0x7fffu + ((u >> 16) & 1u);
}
__device__ __forceinline__ unsigned pack2(float lo, float hi) {  // [hi|lo] bf16 pair
#if __has_builtin(__builtin_amdgcn_cvt_pk_bf16_f32)
    auto p = __builtin_amdgcn_cvt_pk_bf16_f32(lo, hi);
    unsigned w; __builtin_memcpy(&w, &p, 4); return w;
#else
    return __builtin_amdgcn_perm(bfround(hi), bfround(lo), 0x07060302);
#endif
}
__device__ __forceinline__ void lds_barrier() {
    asm volatile("s_waitcnt lgkmcnt(0)\n\ts_barrier" ::: "memory");
}

// fragls per set: [buf 0/1][cg 0..3][lane]x16B. Wave W4 writes cg=W4 (its
// packed next-state frag), keeps a register copy (bs), reads the other 3.
// af[m][i]: chain slot i -> cg {W4, c1, c2, c3} (others ascending).

template<bool FWD, int PH>
__device__ __forceinline__ void phase(int t, float& Dacc,
                                      float4 (&up)[4][2],
                                      const bf16x8 (&af)[2][4],
                                      bf16x8& bs,
                                      short* fset, float* sb2,
                                      const float* pu,
                                      float* cl, float* dc,
                                      int o0, int o1, int o2, int ws,
                                      int cb, int tfin, int W4, int q, int b)
{
    constexpr int CUR  = PH & 1;
    constexpr int NXT  = CUR ^ 1;
    constexpr int SLOT = FWD ? ((1 + PH) & 3) : ((3 - PH) & 3);

    // partner frags (slots 1..3) + lag-1 scale from LDS buf CUR; issue the
    // reads first so the self-frag MFMAs below hide their latency
    bf16x8 bo0 = *(const bf16x8*)(fset + CUR * 2048 + o0);
    bf16x8 bo1 = *(const bf16x8*)(fset + CUR * 2048 + o1);
    bf16x8 bo2 = *(const bf16x8*)(fset + CUR * 2048 + o2);
    float sprev = sb2[CUR * 16 + b];

    // ---- 8 MFMA: 2 m-tiles x 2 depth-2 chains, self slot issues first ----
    f32x4 ae0, ae1, ao0, ao1;
    ae0 = __builtin_amdgcn_mfma_f32_16x16x32_bf16(af[0][0], bs,  (f32x4){0.f,0.f,0.f,0.f}, 0, 0, 0);
    ae1 = __builtin_amdgcn_mfma_f32_16x16x32_bf16(af[1][0], bs,  (f32x4){0.f,0.f,0.f,0.f}, 0, 0, 0);
    ao0 = __builtin_amdgcn_mfma_f32_16x16x32_bf16(af[0][1], bo0, (f32x4){0.f,0.f,0.f,0.f}, 0, 0, 0);
    ao1 = __builtin_amdgcn_mfma_f32_16x16x32_bf16(af[1][1], bo0, (f32x4){0.f,0.f,0.f,0.f}, 0, 0, 0);
    ae0 = __builtin_amdgcn_mfma_f32_16x16x32_bf16(af[0][2], bo1, ae0, 0, 0, 0);
    ae1 = __builtin_amdgcn_mfma_f32_16x16x32_bf16(af[1][2], bo1, ae1, 0, 0, 0);
    ao0 = __builtin_amdgcn_mfma_f32_16x16x32_bf16(af[0][3], bo2, ao0, 0, 0, 0);
    ao1 = __builtin_amdgcn_mfma_f32_16x16x32_bf16(af[1][3], bo2, ao1, 0, 0, 0);

    // u from ring; exp2 issues under MFMA latency (trans pipe)
    float ex[2][4];
    #pragma unroll
    for (int m = 0; m < 2; ++m) {
        float4 v = up[SLOT][m];
        ex[m][0] = __builtin_amdgcn_exp2f(v.x * L2E);
        ex[m][1] = __builtin_amdgcn_exp2f(v.y * L2E);
        ex[m][2] = __builtin_amdgcn_exp2f(v.z * L2E);
        ex[m][3] = __builtin_amdgcn_exp2f(v.w * L2E);
    }
    {   // prefetch into the freed slot (consumed 4 steps later)
        int tp = FWD ? (t + 4) : (t - 5);
        tp = tp < 0 ? 0 : (tp > LL - 1 ? LL - 1 : tp);
        const float* pt = pu + (size_t)tp * TT;
        up[SLOT][0] = *(const float4*)(pt);
        up[SLOT][1] = *(const float4*)(pt + 16);
    }

    // lag-1 renorm scalars (uniform per batch column b)
    float ci = __builtin_amdgcn_rcpf(sprev);
    float lg = __builtin_amdgcn_logf(sprev);          // v_log_f32 = log2
    bool inj = (!FWD) && (tfin == t - 1);
    float cis  = inj ? 0.f : ci;
    float injf = inj ? 1.f : 0.f;
    Dacc = inj ? 0.f : (Dacc + lg);

    f32x4 a0 = ae0 + ao0;
    f32x4 a1 = ae1 + ao1;

    float rv[2][4];
    #pragma unroll
    for (int r = 0; r < 4; ++r) {
        rv[0][r] = cis * a0[r] + injf;                // inj folded into fma
        rv[1][r] = cis * a1[r] + injf;
    }

    if (!FWD) {
        bool cap = (cb == t - 1) && (cb != tfin);     // cap => !inj
        if (__any(cap)) {
            if (cap) {
                float4 c0 = {rv[0][0], rv[0][1], rv[0][2], rv[0][3]};
                float4 c1 = {rv[1][0], rv[1][1], rv[1][2], rv[1][3]};
                *(float4*)(cl + b * TT + 32 * W4 + q * 4)      = c0;
                *(float4*)(cl + b * TT + 32 * W4 + 16 + q * 4) = c1;
                if (W4 == 0 && q == 0) dc[b] = Dacc;
            }
        }
    }

    float ov[2][4];
    #pragma unroll
    for (int r = 0; r < 4; ++r) {
        ov[0][r] = ex[0][r] * rv[0][r];
        ov[1][r] = ex[1][r] * rv[1][r];
    }

    if (FWD) {
        bool cap = (cb == t);
        if (__any(cap)) {
            if (cap) {
                float4 c0 = {ov[0][0], ov[0][1], ov[0][2], ov[0][3]};
                float4 c1 = {ov[1][0], ov[1][1], ov[1][2], ov[1][3]};
                *(float4*)(cl + b * TT + 32 * W4 + q * 4)      = c0;
                *(float4*)(cl + b * TT + 32 * W4 + 16 + q * 4) = c1;
                if (W4 == 0 && q == 0) dc[b] = Dacc;
            }
        }
    }

    // raw S0 for next step's renorm: global row 0 = wave 0, m=0, q=0, reg 0
    if (W4 == 0 && q == 0) sb2[NXT * 16 + b] = a0[0];

    // pack self next-state frag (identity: frag W4 <- m-tiles {0,1} here)
    bfrw pk;
    pk.w[0] = pack2(ov[0][0], ov[0][1]);
    pk.w[1] = pack2(ov[0][2], ov[0][3]);
    pk.w[2] = pack2(ov[1][0], ov[1][1]);
    pk.w[3] = pack2(ov[1][2], ov[1][3]);
    bs = pk.v;
    *(bf16x8*)(fset + NXT * 2048 + ws) = pk.v;

    lds_barrier();
}

__launch_bounds__(512, 1)
__global__ void crf_scan(const float* __restrict__ inputs,
                         const int*   __restrict__ tags,
                         const int*   __restrict__ slens,
                         const float* __restrict__ trans,
                         float* __restrict__ qcap, float* __restrict__ rcap,
                         float* __restrict__ dqv,  float* __restrict__ drv,
                         int* __restrict__ perm, float* __restrict__ scorebuf)
{
    __shared__ __align__(16) short fragls[2][2][4][64 * 8];   // 16 KB
    __shared__ __align__(16) float capl[2][16][TT];           // 16 KB
    __shared__ float dcap[2][16];
    __shared__ float sbuf[2][2][16];
    __shared__ float ssb[8];
    __shared__ int keys[B_];

    const int tid = threadIdx.x;

    // ---------------- score blocks (16..79): 4 batches each ----------------
    if (blockIdx.x >= NBLK) {
        const int sbid = blockIdx.x - NBLK;         // 0..63
        const int lane = tid & 63, w = tid >> 6;
        #pragma unroll 1
        for (int bi = 0; bi < 4; ++bi) {
            const int b = sbid * 4 + bi;
            const int slen = slens[b];
            const float* inb  = inputs + (size_t)b * LL * TT;
            const int*   tagb = tags + b * LL;
            float sc = 0.f;
            for (int t = tid; t < slen; t += 512) {
                int tg = tagb[t];
                float v = inb[(size_t)t * TT + tg];
                if (t >= 1) v += trans[tagb[t - 1] * TT + tg];
                sc += v;
            }
            #pragma unroll
            for (int off = 32; off > 0; off >>= 1) sc += __shfl_xor(sc, off, 64);
            if (lane == 0) ssb[w] = sc;
            __syncthreads();
            if (tid == 0) scorebuf[b] = ssb[0] + ssb[1] + ssb[2] + ssb[3]
                                      + ssb[4] + ssb[5] + ssb[6] + ssb[7];
            __syncthreads();
        }
        return;
    }

    // ---------------- merged scan blocks (0..15) ----------------
    const int g = blockIdx.x;

    // deterministic bitonic sort of (slen, batch) keys (256 keys, 512 thr)
    if (tid < 256) keys[tid] = slens[tid] * 256 + tid;
    __syncthreads();
    for (int k = 2; k <= B_; k <<= 1) {
        for (int s = k >> 1; s > 0; s >>= 1) {
            if (tid < 256) {
                int ixj = tid ^ s;
                if (ixj > tid) {
                    int a = keys[tid], b2 = keys[ixj];
                    bool asc = ((tid & k) == 0);
                    if ((a > b2) == asc) { keys[tid] = b2; keys[ixj] = a; }
                }
            }
            __syncthreads();
        }
    }
    if (tid < 16) perm[g * 16 + tid] = keys[g * 16 + tid] & 255;

    const int set  = tid >> 8;                  // 0 = fwd, 1 = bwd
    const bool isf = (set == 0);
    const int lane = tid & 63;
    const int W4   = __builtin_amdgcn_readfirstlane((tid >> 6) & 3);
    const int q    = lane >> 4;
    const int b    = lane & 15;

    const int key = keys[g * 16 + b];
    const int ob  = key & 255;
    const int sl  = key >> 8;
    int tfin = sl - 1; if (tfin < 1) tfin = 1;

    int tmax = tfin;
    #pragma unroll
    for (int o = 1; o < 16; o <<= 1) {
        int c2 = __shfl_xor(tmax, o, 16); tmax = c2 > tmax ? c2 : tmax;
    }
    tmax = __builtin_amdgcn_readfirstlane(tmax);

    const int C  = (tmax + 4) >> 1;             // balanced cut (>=2)
    const int cb = tfin < C ? tfin : C;

    int cmax = cb, cmin = cb;
    #pragma unroll
    for (int o = 1; o < 16; o <<= 1) {
        int a = __shfl_xor(cmax, o, 16); cmax = a > cmax ? a : cmax;
        int b2 = __shfl_xor(cmin, o, 16); cmin = b2 < cmin ? b2 : cmin;
    }
    cmax = __builtin_amdgcn_readfirstlane(cmax);
    cmin = __builtin_amdgcn_readfirstlane(cmin);

    const int tb0 = (tmax + 4) & ~3;            // bwd start, == 0 mod 4
    const int nif = (cmax + 3) >> 2;
    const int nib = (tb0 - cmin + 3) >> 2;
    const int NS  = nif > nib ? nif : nib;      // shared iteration count

    // slot -> cg mapping: {W4, others ascending}
    const int c1 = (W4 == 0) ? 1 : 0;
    const int c2 = (W4 <= 1) ? 2 : 1;
    const int c3 = (W4 <= 2) ? 3 : 2;
    const int o0 = (c1 * 64 + lane) * 8;
    const int o1 = (c2 * 64 + lane) * 8;
    const int o2 = (c3 * 64 + lane) * 8;
    const int ws = (W4 * 64 + lane) * 8;

    // E fragments: af[m][i], slot i -> cg {W4,c1,c2,c3};
    // j = 32*W4 + 16m + b; k = 32c + 16*(jj>>2) + 4q + (jj&3) (verified)
    bf16x8 af[2][4];
    #pragma unroll
    for (int m = 0; m < 2; ++m) {
        const int j = 32 * W4 + 16 * m + b;
        #pragma unroll
        for (int i = 0; i < 4; ++i) {
            const int c = (i == 0) ? W4 : (i == 1) ? c1 : (i == 2) ? c2 : c3;
            #pragma unroll
            for (int jj = 0; jj < 8; ++jj) {
                int k = 32 * c + 16 * (jj >> 2) + 4 * q + (jj & 3);
                int idx = isf ? (k * TT + j) : (j * TT + k);
                float ev = __builtin_amdgcn_exp2f(trans[idx] * L2E);
                af[m][i][jj] = (short)(bfround(ev) >> 16);
            }
        }
    }

    short* fset = &fragls[set][0][0][0];
    float* sb2  = &sbuf[set][0][0];
    float* cl   = &capl[set][0][0];
    float* dc   = &dcap[set][0];

    const float* pu = inputs + (size_t)ob * LL * TT + 32 * W4 + q * 4;
    float Dacc = 0.f;
    float4 up[4][2];
    bf16x8 bs;

    if (W4 == 0 && lane < 16) sb2[lane] = 1.0f;     // initial scale (buf 0)

    if (isf) {
        // init q0 = exp(in[0][j]) -> self frag + LDS buf0 (cb>=1: no init cap)
        float q0[2][4];
        #pragma unroll
        for (int m = 0; m < 2; ++m) {
            float4 v = *(const float4*)(pu + m * 16);
            q0[m][0] = __builtin_amdgcn_exp2f(v.x * L2E);
            q0[m][1] = __builtin_amdgcn_exp2f(v.y * L2E);
            q0[m][2] = __builtin_amdgcn_exp2f(v.z * L2E);
            q0[m][3] = __builtin_amdgcn_exp2f(v.w * L2E);
        }
        bfrw pk;
        pk.w[0] = pack2(q0[0][0], q0[0][1]);
        pk.w[1] = pack2(q0[0][2], q0[0][3]);
        pk.w[2] = pack2(q0[1][0], q0[1][1]);
        pk.w[3] = pack2(q0[1][2], q0[1][3]);
        bs = pk.v;
        *(bf16x8*)(fset + ws) = pk.v;

        #pragma unroll
        for (int s = 1; s <= 4; ++s) {
            up[s & 3][0] = *(const float4*)(pu + (size_t)s * TT);
            up[s & 3][1] = *(const float4*)(pu + (size_t)s * TT + 16);
        }
    } else {
        // init w = 1.0; batches with cb == tfin capture ones / Dr = 0 here
        bfrw pk;
        pk.w[0] = pk.w[1] = pk.w[2] = pk.w[3] = 0x3F803F80u;
        bs = pk.v;
        *(bf16x8*)(fset + ws) = pk.v;
        if (cb == tfin) {
            float4 one4 = {1.f, 1.f, 1.f, 1.f};
            *(float4*)(cl + b * TT + 32 * W4 + q * 4)      = one4;
            *(float4*)(cl + b * TT + 32 * W4 + 16 + q * 4) = one4;
            if (W4 == 0 && q == 0) dc[b] = 0.f;
        }
        #pragma unroll
        for (int ph = 0; ph < 4; ++ph) {
            int ui = tb0 - 1 - ph;
            ui = ui > LL - 1 ? LL - 1 : (ui < 0 ? 0 : ui);
            up[(3 - ph) & 3][0] = *(const float4*)(pu + (size_t)ui * TT);
            up[(3 - ph) & 3][1] = *(const float4*)(pu + (size_t)ui * TT + 16);
        }
    }
    __syncthreads();

    if (isf) {
        for (int i = 0; i < NS; ++i) {
            const int tb = 1 + 4 * i;
            phase<true,0>(tb+0, Dacc, up, af, bs, fset, sb2, pu, cl, dc, o0,o1,o2,ws, cb, tfin, W4, q, b);
            phase<true,1>(tb+1, Dacc, up, af, bs, fset, sb2, pu, cl, dc, o0,o1,o2,ws, cb, tfin, W4, q, b);
            phase<true,2>(tb+2, Dacc, up, af, bs, fset, sb2, pu, cl, dc, o0,o1,o2,ws, cb, tfin, W4, q, b);
            phase<true,3>(tb+3, Dacc, up, af, bs, fset, sb2, pu, cl, dc, o0,o1,o2,ws, cb, tfin, W4, q, b);
        }
    } else {
        for (int i = 0; i < NS; ++i) {
            const int tb = tb0 - 4 * i;
            phase<false,0>(tb-0, Dacc, up, af, bs, fset, sb2, pu, cl, dc, o0,o1,o2,ws, cb, tfin, W4, q, b);
            phase<false,1>(tb-1, Dacc, up, af, bs, fset, sb2, pu, cl, dc, o0,o1,o2,ws, cb, tfin, W4, q, b);
            phase<false,2>(tb-2, Dacc, up, af, bs, fset, sb2, pu, cl, dc, o0,o1,o2,ws, cb, tfin, W4, q, b);
            phase<false,3>(tb-3, Dacc, up, af, bs, fset, sb2, pu, cl, dc, o0,o1,o2,ws, cb, tfin, W4, q, b);
        }
    }

    // copy captures out (last lds_barrier drained + synced everything)
    float* gout = isf ? qcap : rcap;
    const int ltid = tid & 255;
    #pragma unroll
    for (int i = 0; i < 2; ++i) {
        float4 v = *(const float4*)(cl + i * 1024 + ltid * 4);
        *(float4*)(gout + (size_t)g * 16 * TT + i * 1024 + ltid * 4) = v;
    }
    if (ltid < 16) (isf ? dqv : drv)[g * 16 + ltid] = dc[ltid];
}

__global__ void crf_comb(const float* __restrict__ qcap, const float* __restrict__ rcap,
                         const float* __restrict__ dqv, const float* __restrict__ drv,
                         const int* __restrict__ perm, const float* __restrict__ scorebuf,
                         float* __restrict__ out) {
    const int tid = threadIdx.x;
    const int r16 = tid >> 4, part = tid & 15;
    const int rank = blockIdx.x * 16 + r16;
    const float* qc = qcap + rank * TT + part * 8;
    const float* rc = rcap + rank * TT + part * 8;
    float4 a0 = *(const float4*)(qc);
    float4 a1 = *(const float4*)(qc + 4);
    float4 b0 = *(const float4*)(rc);
    float4 b1 = *(const float4*)(rc + 4);
    float s = a0.x*b0.x + a0.y*b0.y + a0.z*b0.z + a0.w*b0.w
            + a1.x*b1.x + a1.y*b1.y + a1.z*b1.z + a1.w*b1.w;
    #pragma unroll
    for (int o = 1; o < 16; o <<= 1) s += __shfl_xor(s, o, 16);
    if (part == 0) {
        int ob = perm[rank];
        float logZ = LN2f * (__builtin_amdgcn_logf(s) + dqv[rank] + drv[rank]);
        out[ob] = scorebuf[ob] - logZ;
    }
}

extern "C" void kernel_launch(void* const* d_in, const int* in_sizes, int n_in,
                              void* d_out, int out_size, void* d_ws, size_t ws_size,
                              hipStream_t stream) {
    const float* inputs = (const float*)d_in[0];
    const int*   tags   = (const int*)d_in[1];
    const int*   slens  = (const int*)d_in[2];
    const float* trans  = (const float*)d_in[3];
    float* out = (float*)d_out;

    float* qcap = (float*)d_ws;            // 256*128 f32
    float* rcap = qcap + 32768;            // 256*128 f32
    float* dqv  = rcap + 32768;            // 256
    float* drv  = dqv + 256;               // 256
    int*   perm = (int*)(drv + 256);       // 256
    float* scorebuf = (float*)(perm + 256);// 256

    crf_scan<<<NBLK + 64, 512, 0, stream>>>(inputs, tags, slens, trans,
                                            qcap, rcap, dqv, drv, perm, scorebuf);
    crf_comb<<<NBLK, 256, 0, stream>>>(qcap, rcap, dqv, drv, perm, scorebuf, out);
}